// Round 8
// baseline (152.985 us; speedup 1.0000x reference)
//
#include <hip/hip_runtime.h>
#include <hip/hip_bf16.h>

typedef __bf16 bf16x8 __attribute__((ext_vector_type(8)));
typedef float f32x4 __attribute__((ext_vector_type(4)));
typedef float f32x16 __attribute__((ext_vector_type(16)));
typedef unsigned short u16;
typedef unsigned int u32;

__device__ __forceinline__ u16 f2bf_rne(float f){
  union { float f; u32 u; } v; v.f = f;
  u32 r = v.u + 0x7fffu + ((v.u >> 16) & 1u);
  return (u16)(r >> 16);
}
// pack hi16(a)|hi16(b)<<16 in ONE v_perm_b32 (truncation; P feeds attention weights)
__device__ __forceinline__ u32 pack2(float a, float b){
  return __builtin_amdgcn_perm(__float_as_uint(a), __float_as_uint(b), 0x03020706u);
}
// async global->LDS, 16B per lane (dest = wave-uniform base + lane*16)
__device__ __forceinline__ void load_lds16(const void* g, void* l){
  __builtin_amdgcn_global_load_lds((const __attribute__((address_space(1))) void*)g,
                                   (__attribute__((address_space(3))) void*)l, 16, 0, 0);
}
// workgroup barrier WITHOUT vmcnt drain (LDS visibility only): in-flight global
// loads (V register prefetches, K stages) ride through; vmcnt gated separately.
#define BARRIER_LGKM() asm volatile("s_waitcnt lgkmcnt(0)\n\ts_barrier" ::: "memory")

// ------------- prep: Wfrag = [Wh|Wf|Wg]^T in MFMA B-fragment order -------------
// Wfrag[cc(20)][kk(8)][lane(64)][j(8)] bf16; lane=(quad,L):
//   element = Wcat[k = kk*32 + quad*8 + j][n = cc*16 + L]
__global__ __launch_bounds__(512) void prep_kernel(
    const float* __restrict__ Wf, const float* __restrict__ Wg,
    const float* __restrict__ Wh, u16* __restrict__ Wfrag){
  const int cc = blockIdx.x;             // 20
  const int t = threadIdx.x;             // 512 = kk(8) x lane(64)
  const int kk = t >> 6, lane = t & 63;
  const int L = lane & 15, quad = lane >> 4;
  const int n = cc * 16 + L;
  u32 pk[4];
  #pragma unroll
  for (int j2 = 0; j2 < 4; ++j2){
    float v[2];
    #pragma unroll
    for (int h = 0; h < 2; ++h){
      int k = kk * 32 + quad * 8 + j2 * 2 + h;
      if (n < 256)      v[h] = Wh[k * 256 + n];
      else if (n < 288) v[h] = Wf[k * 32 + (n - 256)];
      else              v[h] = Wg[k * 32 + (n - 288)];
    }
    pk[j2] = (u32)f2bf_rne(v[0]) | ((u32)f2bf_rne(v[1]) << 16);
  }
  uint4* dst = (uint4*)(Wfrag + ((size_t)(cc * 8 + kk) * 64 + lane) * 8);
  *dst = make_uint4(pk[0], pk[1], pk[2], pk[3]);
}

// ---------------- projection: h/f/g via MFMA, 512 thr / 8 waves ----------------
// Qg pre-scaled by log2(e), row-major [row][32]. K written FRAGMENT-MAJOR:
// Kfrag[tile(256)][frag(4)][512]; within chunk: (c>>3)*128 + (row&15)*8 + (c&7)
// so flash's ds_read Ks[chunk][lane*8+j] (lane=quad*16+L) yields
// K[tile*64 + frag*16 + L][quad*8 + j] (verified elementwise, e.g. K[70][9]).
// V emitted fragment-major per 64-row group: Vfrag[g64][p(8)][c(256)][j(8)],
// p = ((tn&15)<<2)|(tn>>4).
__global__ __launch_bounds__(512) void proj_kernel(
    const float* __restrict__ x, const u16* __restrict__ Wfrag,
    u16* __restrict__ Qg, u16* __restrict__ Kfrag, u16* __restrict__ Vfrag)
{
  __shared__ __align__(16) u16 smem[256 * 72];   // 36 KB, two phases
  u16 (*xb)[264] = (u16(*)[264])smem;
  u16 (*Vr)[72]  = (u16(*)[72])smem;

  const int tid = threadIdx.x;
  const int lane = tid & 63, wave = tid >> 6;
  const int L = lane & 15, quad = lane >> 4;
  const int rowgrp = wave >> 1, colhalf = wave & 1;
  const int n0 = blockIdx.x * 64;

  const float4* xsrc = (const float4*)(x + (size_t)n0 * 256);
  #pragma unroll
  for (int j = 0; j < 8; ++j){
    int idx = j * 512 + tid;
    int row = idx >> 6, col4 = idx & 63;
    float4 v = xsrc[idx];
    u32 p0 = (u32)f2bf_rne(v.x) | ((u32)f2bf_rne(v.y) << 16);
    u32 p1 = (u32)f2bf_rne(v.z) | ((u32)f2bf_rne(v.w) << 16);
    *(uint2*)&xb[row][col4 * 4] = make_uint2(p0, p1);
  }
  __syncthreads();

  f32x4 acc[10];
  #pragma unroll
  for (int cc = 0; cc < 10; ++cc) acc[cc] = (f32x4){0.f, 0.f, 0.f, 0.f};

  #pragma unroll
  for (int kk = 0; kk < 8; ++kk){
    bf16x8 a = *(const bf16x8*)&xb[rowgrp * 16 + L][kk * 32 + quad * 8];
    #pragma unroll
    for (int cc = 0; cc < 10; ++cc){
      int ccg = colhalf * 10 + cc;
      bf16x8 bfr = *(const bf16x8*)(Wfrag + ((size_t)(ccg * 8 + kk) * 64 + lane) * 8);
      acc[cc] = __builtin_amdgcn_mfma_f32_16x16x32_bf16(a, bfr, acc[cc], 0, 0, 0);
    }
  }

  if (colhalf){
    #pragma unroll
    for (int cc = 6; cc < 10; ++cc){
      int ccg = 10 + cc;                                  // 16..19
      int c = (ccg & 1) * 16 + L;                         // d within 0..31
      #pragma unroll
      for (int r = 0; r < 4; ++r){
        int row = n0 + rowgrp * 16 + quad * 4 + r;
        if (ccg < 18){
          // K = f -> fragment-major store
          size_t off = ((size_t)(row >> 6) * 4 + ((row >> 4) & 3)) * 512
                     + (c >> 3) * 128 + (row & 15) * 8 + (c & 7);
          Kfrag[off] = f2bf_rne(acc[cc][r]);
        } else {
          // Q = g, pre-scaled by log2(e), row-major
          Qg[(size_t)row * 32 + c] = f2bf_rne(acc[cc][r] * 1.44269504088896f);
        }
      }
    }
  }

  __syncthreads();   // xb consumed; reuse smem as Vr

  {
    const int cmax = colhalf ? 6 : 10;
    for (int cc = 0; cc < cmax; ++cc){
      int ccg = colhalf * 10 + cc;
      int c = ccg * 16 + L;
      #pragma unroll
      for (int r = 0; r < 4; ++r){
        int tn = rowgrp * 16 + quad * 4 + r;
        int p  = ((tn & 15) << 2) | (tn >> 4);
        Vr[c][p] = f2bf_rne(acc[cc][r]);
      }
    }
  }
  __syncthreads();

  u16* Vblk = Vfrag + (size_t)blockIdx.x * (256 * 64);
  #pragma unroll
  for (int i = 0; i < 4; ++i){
    int idx = i * 512 + tid;
    *(uint4*)(Vblk + (size_t)idx * 8) = *(const uint4*)&Vr[idx & 255][(idx >> 8) * 8];
  }
}

// ------- flash: q64, 2 k-halves, 2 tiles/barrier, K via LDS (dedup) ------------
// MODEL (R0-R6): time/iter = max(floor ~2800+MFMA, issued-bytes / ~24.6 B/cyc/CU).
// R0 was exactly balanced (96KB/iter = 3997cyc = floor) -> neither reorder (R1),
// TLP (R3), nor unroll alone (R6: 192KB -> mem-bound 8550) could win. This cuts
// ISSUED bytes while keeping unroll-2's floor amortization: K was 4x duplicate-
// issued per half; now staged ONCE per tile-pair into LDS from fragment-major
// Kfrag, all waves ds_read fragments (linear b128). Per body: V 128KB + K 16KB
// = 144KB vs R6's 192KB -> mem term ~5850cyc -> 16 bodies ~ 94K cyc ~ 39us.
// R7 BUG FIXED HERE: chunk staging used global wave id (0..7) as chunk index,
// so each half-slab only got 4 of its 8 chunks (other half uninitialized ->
// NaN). Now wave wv (0..3) of each half stages chunks 2wv, 2wv+1 of ITS half's
// slab (2 load_lds16 per wave per slab); 4 waves x 2 = full 8-chunk coverage.
// vmcnt discipline (2 stage ops/wave/body): prologue issues [qa][4 stages]
// [16 vfc] = 21 outstanding; vmcnt(18) drains qa + pair0's 2 stages. Steady
// state at body it's wait: [stage(it+2) x2][vfc(it) x16][stage(it+1) x2] = 20;
// vmcnt(18) drains exactly stage(it+1). Dummy stages at it>=14 keep counts
// uniform. Slab it&1 rewritten at body it, one full lgkm-drained barrier after
// its last ds_reads (body it-1).
__global__ __launch_bounds__(512) void flash_kernel(
    const u16* __restrict__ Qg, const u16* __restrict__ Kfrag, const u16* __restrict__ Vfrag,
    const float* __restrict__ x, const float* __restrict__ gamma, float* __restrict__ out)
{
  constexpr float SH = -92.33248261689366f;      // -64*log2(e); s already log2-scaled
  __shared__ __align__(16) char smem[73728];     // Plds 73728 B, overlaid by Osh 64 KB
  u16 (*Plds)[2][2][64][72] = (u16 (*)[2][2][64][72])smem;  // [half][buf][tile][row][72]
  float (*Osh)[256] = (float (*)[256])smem;
  __shared__ __align__(16) u16 Kl[2][2][8][512]; // [half][slab][chunk][512] = 32 KB
  __shared__ float Lsh[2][64];

  const int tid = threadIdx.x, lane = tid & 63, wave = tid >> 6;
  const int L = lane & 15, quad = lane >> 4;
  const int m32 = lane & 31, h32 = lane >> 5;
  const int half = wave >> 2, wv = wave & 3;

  // XCD swizzle: id&7 -> XCD; 2 XCDs per batch (V+K+Q working set ~2.5MB < 4MB L2)
  const int id = blockIdx.x;                     // 0..255
  const int xcd = id & 7;
  const int b = xcd >> 1;
  const int qt = (xcd & 1) * 32 + (id >> 3);     // 0..63
  const int q0 = qt * 64;

  const u16* Qb = Qg + (size_t)(b * 4096) * 32;
  const u16* Kb = Kfrag + (size_t)b * 131072;    // 64 tiles x 4 frags x 512 u16
  const u16* Vb = Vfrag + (size_t)b * (64 * 256 * 64);
  const float gm = gamma[0];

  const int g0 = half * 32;
  const int c0 = wv * 2;                         // this wave's chunk pair

  // ---- prologue: qa FIRST (vmcnt bookkeeping), then K stages, then vfc ----
  bf16x8 qa = *(const bf16x8*)(Qb + (size_t)(q0 + wv * 16 + L) * 32 + quad * 8);
  asm volatile("" ::: "memory");
  // stage pair0 -> slab0, pair1 -> slab1; wave wv stages chunks c0, c0+1
  {
    const u16* s0 = Kb + ((size_t)(g0 + 0) * 4 + c0) * 512 + lane * 8;
    load_lds16(s0,       &Kl[half][0][c0][0]);
    load_lds16(s0 + 512, &Kl[half][0][c0 + 1][0]);
    const u16* s1 = Kb + ((size_t)(g0 + 2) * 4 + c0) * 512 + lane * 8;
    load_lds16(s1,       &Kl[half][1][c0][0]);
    load_lds16(s1 + 512, &Kl[half][1][c0 + 1][0]);
  }
  asm volatile("" ::: "memory");
  // vfc for pair0 (tiles g0 (A), g0+1 (B))
  bf16x8 vfA[8], vfB[8];
  {
    const u16* Vt = Vb + (size_t)g0 * (256 * 64);
    #pragma unroll
    for (int ks = 0; ks < 4; ++ks){
      const u16* vrow = Vt + (size_t)((ks * 2 + h32) * 256 + wv * 64 + m32) * 8;
      vfA[ks * 2]     = *(const bf16x8*)(vrow);
      vfA[ks * 2 + 1] = *(const bf16x8*)(vrow + 32 * 8);
      vfB[ks * 2]     = *(const bf16x8*)(vrow + 16384);
      vfB[ks * 2 + 1] = *(const bf16x8*)(vrow + 16384 + 32 * 8);
    }
  }
  // wait stage(pair0): newer ops = 2 pair1 stages + 16 vfc = 18
  asm volatile("s_waitcnt vmcnt(18)" ::: "memory");
  bf16x8 kcA0, kcA1, kcA2, kcA3, kcB0, kcB1, kcB2, kcB3;
  {
    const u16 (*Ks)[512] = Kl[half][0];
    kcA0 = *(const bf16x8*)&Ks[0][lane * 8];
    kcA1 = *(const bf16x8*)&Ks[1][lane * 8];
    kcA2 = *(const bf16x8*)&Ks[2][lane * 8];
    kcA3 = *(const bf16x8*)&Ks[3][lane * 8];
    kcB0 = *(const bf16x8*)&Ks[4][lane * 8];
    kcB1 = *(const bf16x8*)&Ks[5][lane * 8];
    kcB2 = *(const bf16x8*)&Ks[6][lane * 8];
    kcB3 = *(const bf16x8*)&Ks[7][lane * 8];
  }

  f32x16 acc[4];                                  // [qi*2+ci]: 64q x 64c
  #pragma unroll
  for (int t = 0; t < 4; ++t)
    #pragma unroll
    for (int i = 0; i < 16; ++i) acc[t][i] = 0.f;
  float lsum[4] = {0.f, 0.f, 0.f, 0.f};
  const f32x4 zero = (f32x4){0.f, 0.f, 0.f, 0.f};

  for (int it = 0; it < 16; ++it){
    u16 (*PwA)[72] = Plds[half][it & 1][0];
    u16 (*PwB)[72] = Plds[half][it & 1][1];

    // ---- QK^T for both tiles from registers (s log2-scaled via Qg) ----
    f32x4 sA0 = __builtin_amdgcn_mfma_f32_16x16x32_bf16(qa, kcA0, zero, 0, 0, 0);
    f32x4 sA1 = __builtin_amdgcn_mfma_f32_16x16x32_bf16(qa, kcA1, zero, 0, 0, 0);
    f32x4 sA2 = __builtin_amdgcn_mfma_f32_16x16x32_bf16(qa, kcA2, zero, 0, 0, 0);
    f32x4 sA3 = __builtin_amdgcn_mfma_f32_16x16x32_bf16(qa, kcA3, zero, 0, 0, 0);
    f32x4 sB0 = __builtin_amdgcn_mfma_f32_16x16x32_bf16(qa, kcB0, zero, 0, 0, 0);
    f32x4 sB1 = __builtin_amdgcn_mfma_f32_16x16x32_bf16(qa, kcB1, zero, 0, 0, 0);
    f32x4 sB2 = __builtin_amdgcn_mfma_f32_16x16x32_bf16(qa, kcB2, zero, 0, 0, 0);
    f32x4 sB3 = __builtin_amdgcn_mfma_f32_16x16x32_bf16(qa, kcB3, zero, 0, 0, 0);

    // ---- p = exp2(s+SH); lsum; packed P stores for both tiles ----
    #pragma unroll
    for (int r = 0; r < 4; ++r){
      float a0 = __builtin_amdgcn_exp2f(sA0[r] + SH);
      float a1 = __builtin_amdgcn_exp2f(sA1[r] + SH);
      float a2 = __builtin_amdgcn_exp2f(sA2[r] + SH);
      float a3 = __builtin_amdgcn_exp2f(sA3[r] + SH);
      float b0 = __builtin_amdgcn_exp2f(sB0[r] + SH);
      float b1 = __builtin_amdgcn_exp2f(sB1[r] + SH);
      float b2 = __builtin_amdgcn_exp2f(sB2[r] + SH);
      float b3 = __builtin_amdgcn_exp2f(sB3[r] + SH);
      lsum[r] += ((a0 + a1) + (a2 + a3)) + ((b0 + b1) + (b2 + b3));
      *(uint2*)&PwA[wv * 16 + quad * 4 + r][L * 4] =
          make_uint2(pack2(a0, a1), pack2(a2, a3));
      *(uint2*)&PwB[wv * 16 + quad * 4 + r][L * 4] =
          make_uint2(pack2(b0, b1), pack2(b2, b3));
    }

    BARRIER_LGKM();   // both P slabs visible; global loads/stages ride through

    // ---- stage K pair (it+2) into slab it&1 (readers drained >=1 barrier ago).
    // it>=14: dummy re-stage (wraps to pair 0/1) to keep vmcnt counts uniform.
    {
      int pp = (it + 2) & 15;
      const u16* ks = Kb + ((size_t)(g0 + pp * 2) * 4 + c0) * 512 + lane * 8;
      load_lds16(ks,       &Kl[half][it & 1][c0][0]);
      load_lds16(ks + 512, &Kl[half][it & 1][c0 + 1][0]);
    }
    asm volatile("" ::: "memory");

    // ---- kc for pair it+1 from slab (it+1)&1; newer ops = 2 stages + 16 vfc ----
    if (it < 15){
      asm volatile("s_waitcnt vmcnt(18)" ::: "memory");
      const u16 (*Ks)[512] = Kl[half][(it + 1) & 1];
      kcA0 = *(const bf16x8*)&Ks[0][lane * 8];
      kcA1 = *(const bf16x8*)&Ks[1][lane * 8];
      kcA2 = *(const bf16x8*)&Ks[2][lane * 8];
      kcA3 = *(const bf16x8*)&Ks[3][lane * 8];
      kcB0 = *(const bf16x8*)&Ks[4][lane * 8];
      kcB1 = *(const bf16x8*)&Ks[5][lane * 8];
      kcB2 = *(const bf16x8*)&Ks[6][lane * 8];
      kcB3 = *(const bf16x8*)&Ks[7][lane * 8];
    }

    // ---- O += P(A) V(A) + P(B) V(B) : af from Plds, vf in registers ----
    #pragma unroll
    for (int ks = 0; ks < 4; ++ks){
      bf16x8 af0 = *(const bf16x8*)&PwA[m32][ks * 16 + h32 * 8];
      bf16x8 af1 = *(const bf16x8*)&PwA[32 + m32][ks * 16 + h32 * 8];
      acc[0] = __builtin_amdgcn_mfma_f32_32x32x16_bf16(af0, vfA[ks*2],   acc[0], 0, 0, 0);
      acc[1] = __builtin_amdgcn_mfma_f32_32x32x16_bf16(af0, vfA[ks*2+1], acc[1], 0, 0, 0);
      acc[2] = __builtin_amdgcn_mfma_f32_32x32x16_bf16(af1, vfA[ks*2],   acc[2], 0, 0, 0);
      acc[3] = __builtin_amdgcn_mfma_f32_32x32x16_bf16(af1, vfA[ks*2+1], acc[3], 0, 0, 0);
    }
    #pragma unroll
    for (int ks = 0; ks < 4; ++ks){
      bf16x8 af0 = *(const bf16x8*)&PwB[m32][ks * 16 + h32 * 8];
      bf16x8 af1 = *(const bf16x8*)&PwB[32 + m32][ks * 16 + h32 * 8];
      acc[0] = __builtin_amdgcn_mfma_f32_32x32x16_bf16(af0, vfB[ks*2],   acc[0], 0, 0, 0);
      acc[1] = __builtin_amdgcn_mfma_f32_32x32x16_bf16(af0, vfB[ks*2+1], acc[1], 0, 0, 0);
      acc[2] = __builtin_amdgcn_mfma_f32_32x32x16_bf16(af1, vfB[ks*2],   acc[2], 0, 0, 0);
      acc[3] = __builtin_amdgcn_mfma_f32_32x32x16_bf16(af1, vfB[ks*2+1], acc[3], 0, 0, 0);
    }

    // ---- vfc for pair it+1 (16 globals; consumed after next barrier) ----
    if (it < 15){
      const u16* Vn = Vb + (size_t)(g0 + (it + 1) * 2) * (256 * 64);
      #pragma unroll
      for (int ks = 0; ks < 4; ++ks){
        const u16* vrow = Vn + (size_t)((ks * 2 + h32) * 256 + wv * 64 + m32) * 8;
        vfA[ks * 2]     = *(const bf16x8*)(vrow);
        vfA[ks * 2 + 1] = *(const bf16x8*)(vrow + 32 * 8);
        vfB[ks * 2]     = *(const bf16x8*)(vrow + 16384);
        vfB[ks * 2 + 1] = *(const bf16x8*)(vrow + 16384 + 32 * 8);
      }
    }
    // no end barrier: per-half Plds double-buffered; reuse gated by next barrier
  }

  // ================= fused epilogue =================
  BARRIER_LGKM();   // all PV ds-reads retired; Plds region reusable as Osh

  // l: reduce 16 partial lanes per (quad,r); rows wv*16+quad*4+r of this half
  #pragma unroll
  for (int r = 0; r < 4; ++r){
    lsum[r] += __shfl_xor(lsum[r], 1);
    lsum[r] += __shfl_xor(lsum[r], 2);
    lsum[r] += __shfl_xor(lsum[r], 4);
    lsum[r] += __shfl_xor(lsum[r], 8);
  }
  if (L == 0){
    #pragma unroll
    for (int r = 0; r < 4; ++r) Lsh[half][wv * 16 + quad * 4 + r] = lsum[r];
  }
  // half 1 deposits its accumulator into Osh (fp32)
  if (half == 1){
    #pragma unroll
    for (int t = 0; t < 4; ++t){
      const int qi = t >> 1, ci = t & 1;
      #pragma unroll
      for (int rg = 0; rg < 16; ++rg){
        int row = qi * 32 + (rg & 3) + 8 * (rg >> 2) + 4 * h32;   // 32x32 C-layout
        Osh[row][wv * 64 + ci * 32 + m32] = acc[t][rg];
      }
    }
  }
  __syncthreads();
  if (wave == 0){   // per-row scale factor gamma / (l0 + l1)
    float li = gm / (Lsh[0][lane] + Lsh[1][lane]);
    Lsh[0][lane] = li;
  }
  __syncthreads();
  // half 0 merges, scales, writes back to Osh
  if (half == 0){
    #pragma unroll
    for (int t = 0; t < 4; ++t){
      const int qi = t >> 1, ci = t & 1;
      #pragma unroll
      for (int rg = 0; rg < 16; ++rg){
        int row = qi * 32 + (rg & 3) + 8 * (rg >> 2) + 4 * h32;
        int col = wv * 64 + ci * 32 + m32;
        Osh[row][col] = (acc[t][rg] + Osh[row][col]) * Lsh[0][row];
      }
    }
  }
  __syncthreads();
  // coalesced: out = Osh + x
  const size_t base = ((size_t)(b * 4096) + q0) * 256;
  const float4* xs = (const float4*)(x + base);
  float4* od = (float4*)(out + base);
  const float4* Of = (const float4*)&Osh[0][0];
  #pragma unroll
  for (int i = 0; i < 8; ++i){
    int idx = i * 512 + tid;
    float4 o = Of[idx], xv = xs[idx];
    o.x += xv.x; o.y += xv.y; o.z += xv.z; o.w += xv.w;
    od[idx] = o;
  }
}

extern "C" void kernel_launch(void* const* d_in, const int* in_sizes, int n_in,
                              void* d_out, int out_size, void* d_ws, size_t ws_size,
                              hipStream_t stream) {
  const float* x     = (const float*)d_in[0];
  const float* Wf    = (const float*)d_in[1];
  const float* Wg    = (const float*)d_in[2];
  const float* Wh    = (const float*)d_in[3];
  const float* gamma = (const float*)d_in[4];
  float* out = (float*)d_out;

  u16* p = (u16*)d_ws;
  u16* Qg    = p;  p += 16384 * 32;               // 1 MB
  u16* Kfrag = p;  p += 256 * 4 * 64 * 8;         // 1 MB, fragment-major (old Kg slot)
  u16* Vfrag = p;  p += 4 * 64 * 256 * 64;        // 8 MB, fragment-major
  u16* Wfrag = p;  p += 20 * 8 * 64 * 8;          // 160 KB, fragment-major

  prep_kernel<<<20, 512, 0, stream>>>(Wf, Wg, Wh, Wfrag);
  proj_kernel<<<256, 512, 0, stream>>>(x, Wfrag, Qg, Kfrag, Vfrag);
  flash_kernel<<<256, 512, 0, stream>>>(Qg, Kfrag, Vfrag, x, gamma, out);
}